// Round 1
// baseline (877.537 us; speedup 1.0000x reference)
//
#include <hip/hip_runtime.h>

#define BATCH 1024
#define NN 264          // graph nodes
#define HIDN 256        // hidden
#define KP 288          // padded k-stride for w1t
#define FLATN 16896     // 132*128
#define POOL_R 132
#define POOL_C 128
#define SUPS 296        // sup LDS row stride (elements): 148 dwords = 20 mod 32 -> ~2-way
#define SMEM_FUSED (HIDN * SUPS * 2 + 96 * 40 * 2)   // 151552 + 7680 = 159232 B

typedef short bf16x8_t __attribute__((ext_vector_type(8)));
typedef float f32x4_t __attribute__((ext_vector_type(4)));
typedef unsigned short u16x4_t __attribute__((ext_vector_type(4)));

__device__ inline unsigned short f2bf(float f) {
  unsigned int u = __float_as_uint(f);
  return (unsigned short)((u + 0x7fffu + ((u >> 16) & 1u)) >> 16);
}

__device__ inline float selu_f(float x) {
  return x > 0.f ? 1.0507009873554805f * x
                 : 1.7580993408473766f * (__expf(x) - 1.f);
}

// ---------- prep: W1 [264,256] -> W1t bf16 [256][288] (zero pad k>=264) ----------
__global__ __launch_bounds__(256) void k_prep_w1t(const float* __restrict__ W1,
                                                  unsigned short* __restrict__ w1t) {
  int idx = blockIdx.x * 256 + threadIdx.x;   // 256*288 total
  int h = idx / KP, k = idx - h * KP;
  w1t[idx] = (k < NN) ? f2bf(W1[(size_t)k * HIDN + h]) : (unsigned short)0;
}

// ---------- prep: fc1_w [16896,128] -> fwt bf16 [128][16896] ----------
__global__ __launch_bounds__(256) void k_prep_fwt(const float* __restrict__ fw,
                                                  unsigned short* __restrict__ fwt) {
  __shared__ float tile[32][33];
  int k0 = blockIdx.x * 32, n0 = blockIdx.y * 32;
  int tid = threadIdx.x;
#pragma unroll
  for (int i = 0; i < 4; ++i) {
    int idx = tid + i * 256;
    int r = idx >> 5, c = idx & 31;
    tile[r][c] = fw[(size_t)(k0 + r) * 128 + n0 + c];
  }
  __syncthreads();
#pragma unroll
  for (int i = 0; i < 4; ++i) {
    int idx = tid + i * 256;
    int r = idx >> 5, c = idx & 31;
    fwt[(size_t)(n0 + r) * FLATN + k0 + c] = f2bf(tile[c][r]);
  }
}

// ---------- fused: per-graph  h = adj_b @ (x_b @ W1), selu, 2x2 pool -> p ----------
// One block per b. Phase 1 computes support^T[h][node] into LDS (bf16).
// Phase 2 multiplies adj_b by it, adds bias, selu, 2x2-avgpools to p[b][132][128].
__global__ __launch_bounds__(512, 2) void k_fused(const float* __restrict__ x,
                                                  const float* __restrict__ adj,
                                                  const unsigned short* __restrict__ w1t,
                                                  const float* __restrict__ b1,
                                                  float* __restrict__ p) {
  extern __shared__ __align__(16) char smem[];
  unsigned short* sup = (unsigned short*)smem;                       // [256][SUPS]
  unsigned short* As  = (unsigned short*)(smem + HIDN * SUPS * 2);   // [96][40]

  const int tid = threadIdx.x;
  const int lane = tid & 63, wv = tid >> 6;          // 8 waves
  const int lm = lane & 15, q8 = (lane >> 4) * 8, q4 = (lane >> 4) * 4;
  const int b = blockIdx.x;
  const float* xb = x + (size_t)b * NN * NN;
  const float* adjb = adj + (size_t)b * NN * NN;

  // zero sup pad columns [264..296) so k0=256 fragment reads are clean
  {
    u16x4_t zz = (u16x4_t)(unsigned short)0;
    for (int i = tid; i < HIDN * 8; i += 512) {      // 256 rows x 8 chunks of 4
      int h = i >> 3, c = (i & 7) << 2;
      *reinterpret_cast<u16x4_t*>(&sup[(size_t)h * SUPS + NN + c]) = zz;
    }
  }

  // ===================== phase 1: support^T = (x_b @ W1)^T into LDS =====================
  for (int m0 = 0; m0 < NN; m0 += 96) {
    f32x4_t acc[6][2];
#pragma unroll
    for (int i = 0; i < 6; ++i)
#pragma unroll
      for (int j = 0; j < 2; ++j) acc[i][j] = (f32x4_t)0.f;

    for (int k0 = 0; k0 < NN; k0 += 32) {
#pragma unroll
      for (int i = 0; i < 2; ++i) {
        int idx = tid + i * 512;                 // 768 float4 slots = 96 rows x 8
        if (idx < 768) {
          int row = idx >> 3, k4 = idx & 7;
          int k = k0 + k4 * 4;
          float4 v = make_float4(0.f, 0.f, 0.f, 0.f);
          if ((m0 + row) < NN && k < NN)
            v = *reinterpret_cast<const float4*>(&xb[(size_t)(m0 + row) * NN + k]);
          u16x4_t pk;
          pk.x = f2bf(v.x); pk.y = f2bf(v.y); pk.z = f2bf(v.z); pk.w = f2bf(v.w);
          *reinterpret_cast<u16x4_t*>(&As[row * 40 + k4 * 4]) = pk;
        }
      }
      __syncthreads();
      bf16x8_t bb[2];
#pragma unroll
      for (int nt = 0; nt < 2; ++nt)
        bb[nt] = *reinterpret_cast<const bf16x8_t*>(
            &w1t[(size_t)(wv * 32 + nt * 16 + lm) * KP + k0 + q8]);
#pragma unroll
      for (int mt = 0; mt < 6; ++mt) {
        bf16x8_t aa = *reinterpret_cast<const bf16x8_t*>(&As[(mt * 16 + lm) * 40 + q8]);
#pragma unroll
        for (int nt = 0; nt < 2; ++nt)
          acc[mt][nt] = __builtin_amdgcn_mfma_f32_16x16x32_bf16(aa, bb[nt], acc[mt][nt], 0, 0, 0);
      }
      __syncthreads();
    }
    // write C (node rows, h cols) transposed into sup[h][node], 4 nodes packed per b64
#pragma unroll
    for (int mt = 0; mt < 6; ++mt) {
      int node = m0 + mt * 16 + q4;              // base of 4 consecutive nodes
      if (node < NN) {
#pragma unroll
        for (int nt = 0; nt < 2; ++nt) {
          int h = wv * 32 + nt * 16 + lm;
          u16x4_t pk;
          pk.x = f2bf(acc[mt][nt].x); pk.y = f2bf(acc[mt][nt].y);
          pk.z = f2bf(acc[mt][nt].z); pk.w = f2bf(acc[mt][nt].w);
          *reinterpret_cast<u16x4_t*>(&sup[(size_t)h * SUPS + node]) = pk;
        }
      }
    }
  }
  // sup writes become visible to all waves at the first __syncthreads of phase 2.

  // ===================== phase 2: adj_b @ support, selu, pool =====================
  for (int m0 = 0; m0 < NN; m0 += 96) {
    f32x4_t acc[6][2];
#pragma unroll
    for (int i = 0; i < 6; ++i)
#pragma unroll
      for (int j = 0; j < 2; ++j) acc[i][j] = (f32x4_t)0.f;

    for (int k0 = 0; k0 < NN; k0 += 32) {
#pragma unroll
      for (int i = 0; i < 2; ++i) {
        int idx = tid + i * 512;
        if (idx < 768) {
          int row = idx >> 3, k4 = idx & 7;
          int k = k0 + k4 * 4;
          float4 v = make_float4(0.f, 0.f, 0.f, 0.f);
          if ((m0 + row) < NN && k < NN)
            v = *reinterpret_cast<const float4*>(&adjb[(size_t)(m0 + row) * NN + k]);
          u16x4_t pk;
          pk.x = f2bf(v.x); pk.y = f2bf(v.y); pk.z = f2bf(v.z); pk.w = f2bf(v.w);
          *reinterpret_cast<u16x4_t*>(&As[row * 40 + k4 * 4]) = pk;
        }
      }
      __syncthreads();
      bf16x8_t bb[2];
#pragma unroll
      for (int nt = 0; nt < 2; ++nt)
        bb[nt] = *reinterpret_cast<const bf16x8_t*>(
            &sup[(size_t)(wv * 32 + nt * 16 + lm) * SUPS + k0 + q8]);
#pragma unroll
      for (int mt = 0; mt < 6; ++mt) {
        bf16x8_t aa = *reinterpret_cast<const bf16x8_t*>(&As[(mt * 16 + lm) * 40 + q8]);
#pragma unroll
        for (int nt = 0; nt < 2; ++nt)
          acc[mt][nt] = __builtin_amdgcn_mfma_f32_16x16x32_bf16(aa, bb[nt], acc[mt][nt], 0, 0, 0);
      }
      __syncthreads();
    }
    // epilogue: bias + selu + 2x2 avgpool -> p
    float bias[2];
#pragma unroll
    for (int nt = 0; nt < 2; ++nt) bias[nt] = b1[wv * 32 + nt * 16 + lm];
#pragma unroll
    for (int mt = 0; mt < 6; ++mt) {
      int mb = m0 + mt * 16 + q4;                // 4-row group base (even)
#pragma unroll
      for (int nt = 0; nt < 2; ++nt) {
        f32x4_t v = acc[mt][nt];
        float s01 = selu_f(v.x + bias[nt]) + selu_f(v.y + bias[nt]);
        float s23 = selu_f(v.z + bias[nt]) + selu_f(v.w + bias[nt]);
        s01 += __shfl_xor(s01, 1);
        s23 += __shfl_xor(s23, 1);
        if (!(lane & 1) && mb < NN) {
          int pm = mb >> 1;
          int pn = (wv * 32 + nt * 16 + lm) >> 1;
          float* pp = &p[((size_t)b * POOL_R + pm) * POOL_C + pn];
          pp[0] = s01 * 0.25f;
          pp[POOL_C] = s23 * 0.25f;
        }
      }
    }
  }
}

// ---------- BN stats: partial sums over 256-row chunks ----------
__global__ __launch_bounds__(256) void k_bnstat(const float* __restrict__ p,
                                                float* __restrict__ psum) {
  int f = blockIdx.x * 256 + threadIdx.x;
  int r0 = blockIdx.y * 256;
  float s = 0.f, ss = 0.f;
#pragma unroll 4
  for (int r = 0; r < 256; ++r) {
    float v = p[(size_t)(r0 + r) * FLATN + f];
    s += v; ss += v * v;
  }
  psum[(size_t)(blockIdx.y * 2) * FLATN + f] = s;
  psum[(size_t)(blockIdx.y * 2 + 1) * FLATN + f] = ss;
}

__global__ __launch_bounds__(256) void k_bnfin(const float* __restrict__ psum,
                                               const float* __restrict__ gamma,
                                               const float* __restrict__ beta,
                                               float* __restrict__ ab,
                                               float* __restrict__ cb) {
  int f = blockIdx.x * 256 + threadIdx.x;
  float s = 0.f, ss = 0.f;
#pragma unroll
  for (int i = 0; i < 4; ++i) {
    s += psum[(size_t)(i * 2) * FLATN + f];
    ss += psum[(size_t)(i * 2 + 1) * FLATN + f];
  }
  float mu = s * (1.f / 1024.f);
  float var = ss * (1.f / 1024.f) - mu * mu;
  float a = rsqrtf(var + 1e-5f) * gamma[f];
  ab[f] = a;
  cb[f] = beta[f] - mu * a;
}

// ---------- fc1 GEMM: l2 += (BN(p)) @ fc1_w  (K-split x8, atomic fp32) ----------
__global__ __launch_bounds__(256) void k_fc1(const float* __restrict__ p,
                                             const float* __restrict__ ab,
                                             const float* __restrict__ cb,
                                             const unsigned short* __restrict__ fwt,
                                             float* __restrict__ l2) {
  __shared__ __align__(16) unsigned short As[32 * 40];
  const int tid = threadIdx.x, lane = tid & 63, wv = tid >> 6;
  const int r0 = blockIdx.x * 32;
  const int kbase = blockIdx.y * 2112;
  const int lm = lane & 15, q8 = (lane >> 4) * 8;
  const int row = tid >> 3, k4 = tid & 7;
  f32x4_t acc[2][2];
#pragma unroll
  for (int i = 0; i < 2; ++i)
#pragma unroll
    for (int j = 0; j < 2; ++j) acc[i][j] = (f32x4_t)0.f;

  for (int it = 0; it < 66; ++it) {
    int k = kbase + it * 32 + k4 * 4;
    float4 v = *reinterpret_cast<const float4*>(&p[(size_t)(r0 + row) * FLATN + k]);
    float4 av = *reinterpret_cast<const float4*>(&ab[k]);
    float4 cv = *reinterpret_cast<const float4*>(&cb[k]);
    u16x4_t pk;
    pk.x = f2bf(v.x * av.x + cv.x);
    pk.y = f2bf(v.y * av.y + cv.y);
    pk.z = f2bf(v.z * av.z + cv.z);
    pk.w = f2bf(v.w * av.w + cv.w);
    *reinterpret_cast<u16x4_t*>(&As[row * 40 + k4 * 4]) = pk;
    __syncthreads();
    int kq = kbase + it * 32 + q8;
    bf16x8_t bb[2], aa[2];
#pragma unroll
    for (int nt = 0; nt < 2; ++nt)
      bb[nt] = *reinterpret_cast<const bf16x8_t*>(
          &fwt[(size_t)(wv * 32 + nt * 16 + lm) * FLATN + kq]);
#pragma unroll
    for (int mt = 0; mt < 2; ++mt)
      aa[mt] = *reinterpret_cast<const bf16x8_t*>(&As[(mt * 16 + lm) * 40 + q8]);
#pragma unroll
    for (int mt = 0; mt < 2; ++mt)
#pragma unroll
      for (int nt = 0; nt < 2; ++nt)
        acc[mt][nt] = __builtin_amdgcn_mfma_f32_16x16x32_bf16(aa[mt], bb[nt], acc[mt][nt], 0, 0, 0);
    __syncthreads();
  }
#pragma unroll
  for (int mt = 0; mt < 2; ++mt) {
    int rb = r0 + mt * 16 + (lane >> 4) * 4;
#pragma unroll
    for (int nt = 0; nt < 2; ++nt) {
      int col = wv * 32 + nt * 16 + lm;
      atomicAdd(&l2[(size_t)(rb + 0) * 128 + col], acc[mt][nt].x);
      atomicAdd(&l2[(size_t)(rb + 1) * 128 + col], acc[mt][nt].y);
      atomicAdd(&l2[(size_t)(rb + 2) * 128 + col], acc[mt][nt].z);
      atomicAdd(&l2[(size_t)(rb + 3) * 128 + col], acc[mt][nt].w);
    }
  }
}

// ---------- head: selu(l2 + fc1_b) . fc2_w + fc2_b -> sigmoid ----------
__global__ __launch_bounds__(128) void k_head(const float* __restrict__ l2,
                                              const float* __restrict__ fc1b,
                                              const float* __restrict__ fc2w,
                                              const float* __restrict__ fc2b,
                                              float* __restrict__ out) {
  int row = blockIdx.x, t = threadIdx.x;
  float v = l2[(size_t)row * 128 + t] + fc1b[t];
  v = selu_f(v) * fc2w[t];
#pragma unroll
  for (int o = 32; o > 0; o >>= 1) v += __shfl_xor(v, o);
  __shared__ float red[2];
  if ((t & 63) == 0) red[t >> 6] = v;
  __syncthreads();
  if (t == 0) {
    float tot = red[0] + red[1] + fc2b[0];
    out[row] = 1.f / (1.f + __expf(-tot));
  }
}

extern "C" void kernel_launch(void* const* d_in, const int* in_sizes, int n_in,
                              void* d_out, int out_size, void* d_ws, size_t ws_size,
                              hipStream_t stream) {
  const float* x     = (const float*)d_in[0];
  const float* adj   = (const float*)d_in[1];
  const float* W1    = (const float*)d_in[2];
  const float* b1    = (const float*)d_in[3];
  const float* gamma = (const float*)d_in[4];
  const float* beta  = (const float*)d_in[5];
  const float* fc1w  = (const float*)d_in[6];
  const float* fc1b  = (const float*)d_in[7];
  const float* fc2w  = (const float*)d_in[8];
  const float* fc2b  = (const float*)d_in[9];
  float* out = (float*)d_out;
  (void)in_sizes; (void)n_in; (void)out_size; (void)ws_size;

  char* ws = (char*)d_ws;
  size_t off = 0;
  auto alloc = [&](size_t bytes) {
    size_t o = off;
    off += (bytes + 255) & ~(size_t)255;
    return o;
  };
  unsigned short* w1t = (unsigned short*)(ws + alloc((size_t)HIDN * KP * 2));
  unsigned short* fwt = (unsigned short*)(ws + alloc((size_t)128 * FLATN * 2));
  float* p    = (float*)(ws + alloc((size_t)BATCH * FLATN * 4));   // 69 MB
  float* psum = (float*)(ws + alloc((size_t)8 * FLATN * 4));
  float* ab   = (float*)(ws + alloc((size_t)FLATN * 4));
  float* cb   = (float*)(ws + alloc((size_t)FLATN * 4));
  float* l2   = (float*)(ws + alloc((size_t)BATCH * 128 * 4));

  static bool s_attr = false;
  if (!s_attr) {
    hipFuncSetAttribute(reinterpret_cast<const void*>(k_fused),
                        hipFuncAttributeMaxDynamicSharedMemorySize, SMEM_FUSED);
    s_attr = true;
  }

  hipLaunchKernelGGL(k_prep_w1t, dim3(288), dim3(256), 0, stream, W1, w1t);
  hipLaunchKernelGGL(k_prep_fwt, dim3(528, 4), dim3(256), 0, stream, fc1w, fwt);
  hipLaunchKernelGGL(k_fused, dim3(BATCH), dim3(512), SMEM_FUSED, stream,
                     x, adj, w1t, b1, p);
  hipLaunchKernelGGL(k_bnstat, dim3(66, 4), dim3(256), 0, stream, p, psum);
  hipLaunchKernelGGL(k_bnfin, dim3(66), dim3(256), 0, stream, psum, gamma, beta, ab, cb);
  hipMemsetAsync(l2, 0, (size_t)BATCH * 128 * 4, stream);
  hipLaunchKernelGGL(k_fc1, dim3(32, 8), dim3(256), 0, stream, p, ab, cb, fwt, l2);
  hipLaunchKernelGGL(k_head, dim3(BATCH), dim3(128), 0, stream, l2, fc1b, fc2w, fc2b, out);
}